// Round 1
// 64.205 us; speedup vs baseline: 1.0155x; 1.0155x over previous
//
#include <hip/hip_runtime.h>
#include <hip/hip_bf16.h>

// GaussianVoxelizer: B=1, G=128 gaussians, F=16 features, N=100*100*8=80000.
// Sum/count formulation (== reference's incremental masked mean).
//
// R7 design (from R6): same survivor-only ballot-compacted staging, but
//  (a) CUBIC TILING: each block = a 4x8x8 voxel brick (footprint
//      3.2 x 6.4 x 5.6) instead of 256 linear voxels (0.8 x 25.6 x 5.6).
//      Tighter AABB -> survivor count L drops ~0.53x. Stores stay fully
//      coalesced: each wave (lx = t>>6) owns one contiguous 64-voxel run
//      (fixed ix, 8 iy x 8 iz).
//  (b) float4-PACKED PARAMS + SOFTWARE PIPELINE: survivor params packed as
//      3 float4 LDS rows; the eval loop prefetches survivor l+1's params
//      (3x ds_read_b128, uniform-address broadcast) while computing l,
//      hiding LDS latency at the ~1 wave/SIMD occupancy this grid gets.
// Survivor sets that contribute (mask=1 anywhere in the brick) are identical
// to R6 (cull is a conservative support bound) and order is ascending-g,
// so per-voxel sums are bit-identical.
//
// Inputs (setup_inputs order):
//   d_in[0] grid_coords (N,3) f32   (unused -- centers recomputed as
//                                    (i+0.5)*0.8+lo, bit-identical to ref)
//   d_in[1] means3d     (1,G,3) f32
//   d_in[2] opacities   (1,G,1) f32
//   d_in[3] features    (1,G,F) f32
//   d_in[4] covariances (1,G,3,3) f32
// Output: dens (N) f32 followed by feats (N,F) f32, concatenated flat.

#define GV_F 16
#define GV_SX 100
#define GV_SY 100
#define GV_SZ 8
#define GV_SYZ (GV_SY * GV_SZ)   // 800
#define GV_LOX (-40.0f)
#define GV_LOY (-40.0f)
#define GV_LOZ (-1.0f)
#define GV_VOX 0.8f
#define GV_GMAX 128

#define GV_TX 4                  // brick: 4 ix
#define GV_TY 8                  // 8 iy
                                 // 8 iz (full z) -> 256 voxels / block
#define GV_NTX (GV_SX / GV_TX)               // 25
#define GV_NTY ((GV_SY + GV_TY - 1) / GV_TY) // 13 (last tile: 4 valid iy)

__global__ __launch_bounds__(256)
void GaussianVoxelizer_40467181863368_kernel(
    const float* __restrict__ means,  // (G,3)
    const float* __restrict__ opac,   // (G)
    const float* __restrict__ feats,  // (G,F)
    const float* __restrict__ covs,   // (G,9)
    float* __restrict__ out_dens,     // (N)
    float* __restrict__ out_feat,     // (N,F)
    int N, int G)
{
    // compacted survivor params, 3 float4 rows per survivor:
    //  [0]={mx,my,mz,op} [1]={k00,k01,k02,k11} [2]={k12,k22,0,0}
    // (k** are coeffs of -0.5*maha; off-diags pre-doubled)
    __shared__ float4 s_p[GV_GMAX][3];
    __shared__ float4 s_f[GV_GMAX][4];   // opacity * features (compacted)
    __shared__ unsigned long long s_mask[4];

    const int t  = threadIdx.x;
    const int wv = t >> 6;
    const int bx = blockIdx.x;           // x-tile: 0..24
    const int by = blockIdx.y;           // y-tile: 0..12

    // ---- Brick AABB over voxel CENTERS ----
    const int ix_lo = bx * GV_TX;
    const int ix_hi = ix_lo + GV_TX - 1;                 // always < 100
    const int iy_lo = by * GV_TY;
    const int iy_hi = min(iy_lo + GV_TY - 1, GV_SY - 1);
    const float bx0 = ((float)ix_lo + 0.5f) * GV_VOX + GV_LOX;
    const float bx1 = ((float)ix_hi + 0.5f) * GV_VOX + GV_LOX;
    const float by0 = ((float)iy_lo + 0.5f) * GV_VOX + GV_LOY;
    const float by1 = ((float)iy_hi + 0.5f) * GV_VOX + GV_LOY;
    const float bz0 = 0.5f * GV_VOX + GV_LOZ;                         // -0.6
    const float bz1 = ((float)(GV_SZ - 1) + 0.5f) * GV_VOX + GV_LOZ;  //  5.0

    // ---- Cull: mean + cov only (same 6 KB read by every block -> L2-hot) ----
    bool flag = false;
    float mx = 0.f, my = 0.f, mz = 0.f;
    float c00 = 0.f, c01 = 0.f, c02 = 0.f, c11 = 0.f, c12 = 0.f, c22 = 0.f;
    if (t < G) {
        mx = means[t * 3 + 0];
        my = means[t * 3 + 1];
        mz = means[t * 3 + 2];
        c00 = covs[t * 9 + 0];
        c01 = covs[t * 9 + 1];
        c02 = covs[t * 9 + 2];
        c11 = covs[t * 9 + 4];
        c12 = covs[t * 9 + 5];
        c22 = covs[t * 9 + 8];
        const float rx = 2.0f * sqrtf(c00) + 1e-3f;   // support bound + fp pad
        const float ry = 2.0f * sqrtf(c11) + 1e-3f;
        const float rz = 2.0f * sqrtf(c22) + 1e-3f;
        flag = (mx - rx <= bx1) && (mx + rx >= bx0) &&
               (my - ry <= by1) && (my + ry >= by0) &&
               (mz - rz <= bz1) && (mz + rz >= bz0);
    }

    const unsigned long long m = __ballot(flag);
    if ((t & 63) == 0) s_mask[wv] = m;
    __syncthreads();

    // ---- Survivor-only staging into compacted slots (ascending g) ----
    if (flag) {
        int pos = 0;
        #pragma unroll
        for (int i = 0; i < 4; ++i) pos += (i < wv) ? __popcll(s_mask[i]) : 0;
        const unsigned long long lt = (t & 63) ? ((1ull << (t & 63)) - 1ull) : 0ull;
        pos += __popcll(m & lt);

        // inverse covariance via adjugate (cov = A*A^T + 0.1I, SPD, det>=1e-3)
        const float m00 = c11 * c22 - c12 * c12;
        const float m01 = c02 * c12 - c01 * c22;
        const float m02 = c01 * c12 - c02 * c11;
        const float det = c00 * m00 + c01 * m01 + c02 * m02;
        const float s = -0.5f / det;
        const float op = opac[t];

        s_p[pos][0] = make_float4(mx, my, mz, op);
        s_p[pos][1] = make_float4(m00 * s,
                                  m01 * (2.0f * s),
                                  m02 * (2.0f * s),
                                  (c00 * c22 - c02 * c02) * s);
        s_p[pos][2] = make_float4((c01 * c02 - c00 * c12) * (2.0f * s),
                                  (c00 * c11 - c01 * c01) * s,
                                  0.0f, 0.0f);

        const float4* fr = (const float4*)(feats + (size_t)t * GV_F);
        #pragma unroll
        for (int q = 0; q < 4; ++q) {
            float4 v = fr[q];
            v.x *= op; v.y *= op; v.z *= op; v.w *= op;
            s_f[pos][q] = v;
        }
    }
    __syncthreads();
    const int L = __popcll(s_mask[0]) + __popcll(s_mask[1]) +
                  __popcll(s_mask[2]) + __popcll(s_mask[3]);

    // ---- Per-voxel evaluation over the compacted list ----
    // thread -> brick voxel: lx = t>>6 (ix), ly = (t>>3)&7 (iy), lz = t&7 (iz)
    const int lx = t >> 6;
    const int ly = (t >> 3) & 7;
    const int lz = t & 7;
    const int ix = ix_lo + lx;
    const int iy = iy_lo + ly;
    const float cx = ((float)ix + 0.5f) * GV_VOX + GV_LOX;
    const float cy = ((float)iy + 0.5f) * GV_VOX + GV_LOY;
    const float cz = ((float)lz + 0.5f) * GV_VOX + GV_LOZ;

    float cnt = 0.0f;
    float sum_d = 0.0f;
    float4 sf0 = make_float4(0.f, 0.f, 0.f, 0.f);
    float4 sf1 = sf0, sf2 = sf0, sf3 = sf0;

    // software pipeline: params for l prefetched at l-1 (uniform broadcast)
    float4 pa, pb, pc;
    if (L > 0) { pa = s_p[0][0]; pb = s_p[0][1]; pc = s_p[0][2]; }
    for (int l = 0; l < L; ++l) {
        const int lp = (l + 1 < L) ? (l + 1) : l;   // clamp (prefetch always)
        const float4 na = s_p[lp][0];
        const float4 nb = s_p[lp][1];
        const float4 nc = s_p[lp][2];

        const float dx = cx - pa.x;
        const float dy = cy - pa.y;
        const float dz = cz - pa.z;
        // tt = -0.5 * maha
        float a = pb.x * dx;
        a = fmaf(pb.y, dy, a);
        a = fmaf(pb.z, dz, a);
        float tt = a * dx;
        float b = pb.w * dy;
        b = fmaf(pc.x, dz, b);
        tt = fmaf(b, dy, tt);
        tt = fmaf(pc.y * dz, dz, tt);
        if (tt >= -2.0f) {                      // maha <= 4
            const float w = __expf(tt);
            cnt += 1.0f;
            sum_d = fmaf(pa.w, w, sum_d);
            const float4 f0 = s_f[l][0];
            const float4 f1 = s_f[l][1];
            const float4 f2 = s_f[l][2];
            const float4 f3 = s_f[l][3];
            sf0.x = fmaf(f0.x, w, sf0.x); sf0.y = fmaf(f0.y, w, sf0.y);
            sf0.z = fmaf(f0.z, w, sf0.z); sf0.w = fmaf(f0.w, w, sf0.w);
            sf1.x = fmaf(f1.x, w, sf1.x); sf1.y = fmaf(f1.y, w, sf1.y);
            sf1.z = fmaf(f1.z, w, sf1.z); sf1.w = fmaf(f1.w, w, sf1.w);
            sf2.x = fmaf(f2.x, w, sf2.x); sf2.y = fmaf(f2.y, w, sf2.y);
            sf2.z = fmaf(f2.z, w, sf2.z); sf2.w = fmaf(f2.w, w, sf2.w);
            sf3.x = fmaf(f3.x, w, sf3.x); sf3.y = fmaf(f3.y, w, sf3.y);
            sf3.z = fmaf(f3.z, w, sf3.z); sf3.w = fmaf(f3.w, w, sf3.w);
        }
        pa = na; pb = nb; pc = nc;
    }

    if (iy < GV_SY) {
        const int n = ix * GV_SYZ + iy * GV_SZ + lz;
        const float inv_c = (cnt > 0.0f) ? (1.0f / cnt) : 0.0f;
        out_dens[n] = sum_d * inv_c;
        float4* fo = (float4*)(out_feat + (size_t)n * GV_F);
        fo[0] = make_float4(sf0.x * inv_c, sf0.y * inv_c, sf0.z * inv_c, sf0.w * inv_c);
        fo[1] = make_float4(sf1.x * inv_c, sf1.y * inv_c, sf1.z * inv_c, sf1.w * inv_c);
        fo[2] = make_float4(sf2.x * inv_c, sf2.y * inv_c, sf2.z * inv_c, sf2.w * inv_c);
        fo[3] = make_float4(sf3.x * inv_c, sf3.y * inv_c, sf3.z * inv_c, sf3.w * inv_c);
    }
}

extern "C" void kernel_launch(void* const* d_in, const int* in_sizes, int n_in,
                              void* d_out, int out_size, void* d_ws, size_t ws_size,
                              hipStream_t stream) {
    const float* means = (const float*)d_in[1];
    const float* opac  = (const float*)d_in[2];
    const float* feats = (const float*)d_in[3];
    const float* covs  = (const float*)d_in[4];

    const int N = in_sizes[0] / 3;       // 80000
    const int G = in_sizes[2];           // B*G = 128 (B=1)

    float* out_dens = (float*)d_out;         // (N)
    float* out_feat = (float*)d_out + N;     // (N,F)

    dim3 grid(GV_NTX, GV_NTY, 1);            // 25 x 13 = 325 bricks
    GaussianVoxelizer_40467181863368_kernel<<<grid, 256, 0, stream>>>(
        means, opac, feats, covs, out_dens, out_feat, N, G);
}